// Round 9
// baseline (470.780 us; speedup 1.0000x reference)
//
#include <hip/hip_runtime.h>
#include <hip/hip_bf16.h>

#define EPSB 1e-5f

typedef short s16x8 __attribute__((ext_vector_type(8)));
typedef float f32x16 __attribute__((ext_vector_type(16)));

// ---------------- workspace layout (bytes) ----------------
//  p1: 128 x [54][260][16]  = 57,507,840 B   (conv1 out / conv2 in)
//  p2: 128 x [29][136][32]  = 32,309,248 B   (conv2 out / conv3 in)
//  p3: 128 x [16][68][64]   = 17,825,792 B   (conv3 out / conv4 in)
#define P1_OFF   0
#define P2_OFF   57507840
#define P3_OFF   89817088
#define L4_OFF   107642880   // 128x32x6x31 f32 NCHW = 3,047,424 B
#define H1_OFF   110690304   // 128x32 f32
#define WT2_OFF  110706688   // [25][32][16] bf16
#define WT3_OFF  110732288   // [25][64][32] bf16
#define WT4_OFF  110834688   // [25][32][64] bf16
#define SS2_OFF  110937088   // 2*32 f32 (scale, shift)
#define SS3_OFF  110937344   // 2*64 f32
#define SS4_OFF  110937856   // 2*32 f32

__device__ __forceinline__ unsigned short bf16bits(float f) {
    __hip_bfloat16 h = __float2bfloat16(f);
    union { __hip_bfloat16 h; unsigned short u; } cv; cv.h = h; return cv.u;
}

// ---- prep bodies (one kernel) ----

template<int HP, int WP, int C, int IH, int IW>
__device__ __forceinline__ void pad_body(__hip_bfloat16* __restrict__ buf, int idx)
{
    if (idx >= 128 * HP * WP) return;
    const int rc = idx % (HP * WP);
    const int row = rc / WP, col = rc % WP;
    const bool pad = (row < 2) | (row >= 2 + IH) | (col < 2) | (col >= 2 + IW);
    if (!pad) return;
    int4* p = reinterpret_cast<int4*>(buf + (size_t)idx * C);
    #pragma unroll
    for (int i = 0; i < C * 2 / 16; ++i) p[i] = int4{0, 0, 0, 0};
}

__device__ __forceinline__ void wtrans_body(const float* __restrict__ src,
                                            __hip_bfloat16* __restrict__ dst,
                                            int CO, int CI, int idx)
{
    if (idx >= CO * CI * 25) return;
    const int co  = idx / (CI * 25);
    const int rem = idx % (CI * 25);
    const int ci  = rem / 25;
    const int tap = rem % 25;
    dst[((size_t)tap * CO + co) * CI + ci] = __float2bfloat16(src[idx]);
}

__device__ __forceinline__ void scsh_body(const float* __restrict__ b,
                                          const float* __restrict__ g,
                                          const float* __restrict__ be,
                                          const float* __restrict__ m,
                                          const float* __restrict__ v,
                                          float* __restrict__ out, int CO, int i)
{
    if (i < CO) {
        const float sc = g[i] * rsqrtf(v[i] + EPSB);
        out[i]      = sc;
        out[CO + i] = fmaf(b[i] - m[i], sc, be[i]);
    }
}

// block ranges: pad1 [0,7020) pad2 [7020,8992) pad3 [8992,9536)
// wt2 [9536,9586) wt3 [9586,9786) wt4 [9786,9986) scsh [9986,9989)
__global__ __launch_bounds__(256)
void prep_kernel(__hip_bfloat16* p1, __hip_bfloat16* p2, __hip_bfloat16* p3,
                 const float* w2, __hip_bfloat16* wt2,
                 const float* w3, __hip_bfloat16* wt3,
                 const float* w4, __hip_bfloat16* wt4,
                 const float* b2, const float* g2, const float* be2,
                 const float* m2, const float* v2, float* ss2,
                 const float* b3, const float* g3, const float* be3,
                 const float* m3, const float* v3, float* ss3,
                 const float* b4, const float* g4, const float* be4,
                 const float* m4, const float* v4, float* ss4)
{
    const int bid = blockIdx.x;
    const int tid = threadIdx.x;
    if      (bid < 7020) pad_body<54, 260, 16, 50, 250>(p1, bid * 256 + tid);
    else if (bid < 8992) pad_body<29, 136, 32, 25, 125>(p2, (bid - 7020) * 256 + tid);
    else if (bid < 9536) pad_body<16,  68, 64, 12,  62>(p3, (bid - 8992) * 256 + tid);
    else if (bid < 9586) wtrans_body(w2, wt2, 32, 16, (bid - 9536) * 256 + tid);
    else if (bid < 9786) wtrans_body(w3, wt3, 64, 32, (bid - 9586) * 256 + tid);
    else if (bid < 9986) wtrans_body(w4, wt4, 32, 64, (bid - 9786) * 256 + tid);
    else {
        const int which = bid - 9986;
        if      (which == 0) scsh_body(b2, g2, be2, m2, v2, ss2, 32, tid);
        else if (which == 1) scsh_body(b3, g3, be3, m3, v3, ss3, 64, tid);
        else                 scsh_body(b4, g4, be4, m4, v4, ss4, 32, tid);
    }
}

// conv1 v4: block = one pooled output row (n, ph). Stage the 6 input rows
// (cols zero-padded to 504) in LDS once; threads read 6x6 windows from LDS
// (stride 8B between lanes -> 2-way bank conflict = free). Even if the
// allocator rematerializes window reads per co-pair, ds_read remat is 1
// inst vs the global path's addr+cndmask+load chain (rounds 4-6: 2.9x).
__global__ __launch_bounds__(256)
void conv1_kernel(const float* __restrict__ x,
                  const float* __restrict__ wgt,   // (16,1,5,5)
                  const float* __restrict__ bias,
                  const float* __restrict__ g,
                  const float* __restrict__ be,
                  const float* __restrict__ m,
                  const float* __restrict__ v,
                  __hip_bfloat16* __restrict__ p1,
                  int n0)
{
    __shared__ float smem[6 * 504];
    const int n   = blockIdx.y + n0;       // 0..127 (b*8 + l)
    const int ph  = blockIdx.x;            // 0..49
    const int tid = threadIdx.x;

    const int b = n >> 3, l = n & 7;
    const float* ib = x + (size_t)b * 400000 + l * 500;
    const int h0 = 2 * ph - 2;             // rows h0..h0+5

    for (int i = tid; i < 6 * 504; i += 256) {
        const int rr = i / 504, cc = i % 504;
        const int hh = h0 + rr, ww = cc - 2;
        const bool ok = (hh >= 0) & (hh < 100) & (ww >= 0) & (ww < 500);
        smem[i] = ok ? ib[hh * 4000 + ww] : 0.0f;
    }
    __syncthreads();

    if (tid >= 250) return;
    const int pw = tid;

    float win[6][6];
    #pragma unroll
    for (int r = 0; r < 6; ++r)
        #pragma unroll
        for (int c = 0; c < 6; ++c)
            win[r][c] = smem[r * 504 + 2 * pw + c];

    int packed[8];
    #pragma unroll
    for (int cp = 0; cp < 8; ++cp) {
        unsigned short hb[2];
        #pragma unroll
        for (int sub = 0; sub < 2; ++sub) {
            const int co = 2 * cp + sub;
            float a0 = 0.f, a1 = 0.f, a2 = 0.f, a3 = 0.f;
            #pragma unroll
            for (int kh = 0; kh < 5; ++kh) {
                #pragma unroll
                for (int kw = 0; kw < 5; ++kw) {
                    const float w = wgt[co * 25 + kh * 5 + kw];
                    a0 = fmaf(w, win[kh  ][kw  ], a0);
                    a1 = fmaf(w, win[kh  ][kw+1], a1);
                    a2 = fmaf(w, win[kh+1][kw  ], a2);
                    a3 = fmaf(w, win[kh+1][kw+1], a3);
                }
            }
            const float sc = g[co] * rsqrtf(v[co] + EPSB);
            const float sh = fmaf(bias[co] - m[co], sc, be[co]);
            #define RA(a) fmaxf(fmaf((a), sc, sh), 0.0f)
            hb[sub] = bf16bits(fmaxf(fmaxf(RA(a0), RA(a1)), fmaxf(RA(a2), RA(a3))));
            #undef RA
        }
        packed[cp] = hb[0] | (hb[1] << 16);
    }

    int4* dst = reinterpret_cast<int4*>(
        p1 + (size_t)n * (54 * 260 * 16) + ((2 + ph) * 260 + (2 + pw)) * 16);
    dst[0] = int4{packed[0], packed[1], packed[2], packed[3]};
    dst[1] = int4{packed[4], packed[5], packed[6], packed[7]};
}

// Generic MFMA conv+BN+ReLU+pool with XCD-aware block swizzle.
// RPW = pool rows per wave. Per (kw,s)-step: NROW=2*RPW+4 B-row loads feed
// 5*2*RPW MFMAs (RPW=4: 12 loads -> 40 MFMAs; round-8 counters showed the
// RPW=2 ratio of 13 loads -> 20 MFMAs left MfmaUtil at 20%, latency-bound).
template<int CI, int CO, int HINP, int WINP, int HOUTP, int WOUTP,
         int PH, int PW, int NT, int NCOT, int RPW, bool NCHW_OUT>
__global__ __launch_bounds__(256)
void conv_mfma(const __hip_bfloat16* __restrict__ pin,
               const __hip_bfloat16* __restrict__ wq,
               const float* __restrict__ scsh,
               void* __restrict__ pout)
{
    constexpr int R = (PH + RPW - 1) / RPW;
    constexpr int NROW = 2 * RPW + 4;
    const int lane = threadIdx.x & 63;
    const int nbk  = gridDim.x;
    const int swz  = (blockIdx.x & 7) * (nbk >> 3) + (blockIdx.x >> 3);
    int t = swz * 4 + (threadIdx.x >> 6);
    const int cot = t % NCOT; t /= NCOT;
    const int wt  = t % NT;   t /= NT;
    const int r   = t % R;    t /= R;
    const int n   = t;
    if (n >= 128) return;

    const int lw = lane & 31, loct = lane >> 5;
    const int co0 = cot * 32;
    const int w0  = wt * 32;

    const __hip_bfloat16* bbase = pin + (size_t)n * (HINP * WINP * CI)
                                + (w0 + lw) * CI + loct * 8;
    const __hip_bfloat16* abase = wq + (co0 + lw) * CI + loct * 8;

    f32x16 acc[2 * RPW];
    #pragma unroll
    for (int q = 0; q < 2 * RPW; ++q) acc[q] = (f32x16){};

    #pragma unroll
    for (int kw = 0; kw < 5; ++kw) {
        #pragma unroll
        for (int s = 0; s < CI / 16; ++s) {
            s16x8 bfr[NROW];
            #pragma unroll
            for (int j = 0; j < NROW; ++j) {
                const int row = (2 * RPW * r + j < HINP) ? (2 * RPW * r + j) : (HINP - 1);
                bfr[j] = *reinterpret_cast<const s16x8*>(bbase + (row * WINP + kw) * CI + s * 16);
            }
            #pragma unroll
            for (int kh = 0; kh < 5; ++kh) {
                const s16x8 a = *reinterpret_cast<const s16x8*>(
                    abase + (size_t)((kh * 5 + kw) * CO) * CI + s * 16);
                #pragma unroll
                for (int q = 0; q < 2 * RPW; ++q)
                    acc[q] = __builtin_amdgcn_mfma_f32_32x32x16_bf16(a, bfr[kh + q], acc[q], 0, 0, 0);
            }
        }
    }

    const int pw = wt * 16 + (lw >> 1);
    const bool act = ((lane & 1) == 0) && (pw < PW);
    #pragma unroll
    for (int p = 0; p < RPW; ++p) {
        const int pr = RPW * r + p;
        const bool rok = (pr < PH);
        #pragma unroll
        for (int reg = 0; reg < 16; ++reg) {
            const int co = co0 + (reg & 3) + 8 * (reg >> 2) + 4 * loct;
            const float sc = scsh[co], sh = scsh[CO + co];
            const float v0 = fmaxf(fmaf(acc[2 * p    ][reg], sc, sh), 0.0f);
            const float v1 = fmaxf(fmaf(acc[2 * p + 1][reg], sc, sh), 0.0f);
            float vm = fmaxf(v0, v1);
            vm = fmaxf(vm, __shfl_xor(vm, 1, 64));
            if (act && rok) {
                if (NCHW_OUT) {
                    ((float*)pout)[(((size_t)n * CO + co) * PH + pr) * PW + pw] = vm;
                } else {
                    ((__hip_bfloat16*)pout)[(size_t)n * (HOUTP * WOUTP * CO)
                        + ((2 + pr) * WOUTP + (2 + pw)) * CO + co] = __float2bfloat16(vm);
                }
            }
        }
    }
}

// h (128, 5952 NCHW f32) @ fw1^T + fb1 -> h1 (128,32)
__global__ __launch_bounds__(64)
void fc1_kernel(const float* __restrict__ h,
                const float* __restrict__ fw1,
                const float* __restrict__ fb1,
                float* __restrict__ h1)
{
    const int n = blockIdx.x;
    const int j = blockIdx.y;
    const int lane = threadIdx.x;
    const float* hp = h   + (size_t)n * 5952;
    const float* wp = fw1 + (size_t)j * 5952;
    float s = 0.0f;
    for (int k = lane; k < 5952; k += 64) s = fmaf(hp[k], wp[k], s);
    #pragma unroll
    for (int off = 32; off > 0; off >>= 1) s += __shfl_down(s, off, 64);
    if (lane == 0) h1[n * 32 + j] = s + fb1[j];
}

__global__ __launch_bounds__(64)
void fc2_mean_kernel(const float* __restrict__ h1,
                     const float* __restrict__ fw2,
                     const float* __restrict__ fb2,
                     float* __restrict__ out)
{
    const int t = threadIdx.x;
    if (t >= 32) return;
    const int b = t >> 1, c = t & 1;
    float s = 0.0f;
    for (int l = 0; l < 8; ++l) {
        const float* hp = h1 + (size_t)(b * 8 + l) * 32;
        #pragma unroll
        for (int j = 0; j < 32; ++j) s = fmaf(hp[j], fw2[c * 32 + j], s);
    }
    out[t] = fmaf(s, 0.125f, fb2[c]);
}

extern "C" void kernel_launch(void* const* d_in, const int* in_sizes, int n_in,
                              void* d_out, int out_size, void* d_ws, size_t ws_size,
                              hipStream_t stream)
{
    const float* x   = (const float*)d_in[0];
    const float* w1  = (const float*)d_in[1];
    const float* b1  = (const float*)d_in[2];
    const float* g1  = (const float*)d_in[3];
    const float* be1 = (const float*)d_in[4];
    const float* m1  = (const float*)d_in[5];
    const float* v1  = (const float*)d_in[6];
    const float* w2  = (const float*)d_in[7];
    const float* b2  = (const float*)d_in[8];
    const float* g2  = (const float*)d_in[9];
    const float* be2 = (const float*)d_in[10];
    const float* m2  = (const float*)d_in[11];
    const float* v2  = (const float*)d_in[12];
    const float* w3  = (const float*)d_in[13];
    const float* b3  = (const float*)d_in[14];
    const float* g3  = (const float*)d_in[15];
    const float* be3 = (const float*)d_in[16];
    const float* m3  = (const float*)d_in[17];
    const float* v3  = (const float*)d_in[18];
    const float* w4  = (const float*)d_in[19];
    const float* b4  = (const float*)d_in[20];
    const float* g4  = (const float*)d_in[21];
    const float* be4 = (const float*)d_in[22];
    const float* m4  = (const float*)d_in[23];
    const float* v4  = (const float*)d_in[24];
    const float* fw1 = (const float*)d_in[25];
    const float* fb1 = (const float*)d_in[26];
    const float* fw2 = (const float*)d_in[27];
    const float* fb2 = (const float*)d_in[28];

    char* ws = (char*)d_ws;
    __hip_bfloat16* p1  = (__hip_bfloat16*)(ws + P1_OFF);
    __hip_bfloat16* p2  = (__hip_bfloat16*)(ws + P2_OFF);
    __hip_bfloat16* p3  = (__hip_bfloat16*)(ws + P3_OFF);
    float*          l4  = (float*)(ws + L4_OFF);
    float*          h1  = (float*)(ws + H1_OFF);
    __hip_bfloat16* wt2 = (__hip_bfloat16*)(ws + WT2_OFF);
    __hip_bfloat16* wt3 = (__hip_bfloat16*)(ws + WT3_OFF);
    __hip_bfloat16* wt4 = (__hip_bfloat16*)(ws + WT4_OFF);
    float*          ss2 = (float*)(ws + SS2_OFF);
    float*          ss3 = (float*)(ws + SS3_OFF);
    float*          ss4 = (float*)(ws + SS4_OFF);

    prep_kernel<<<dim3(9989), 256, 0, stream>>>(
        p1, p2, p3, w2, wt2, w3, wt3, w4, wt4,
        b2, g2, be2, m2, v2, ss2,
        b3, g3, be3, m3, v3, ss3,
        b4, g4, be4, m4, v4, ss4);

    // conv1: block = one pooled row; 4 n-chunks (profiling visibility)
    for (int c = 0; c < 4; ++c)
        conv1_kernel<<<dim3(50, 32), 256, 0, stream>>>(
            x, w1, b1, g1, be1, m1, v1, p1, c * 32);

    // conv2: RPW=4, R=7 (rows 25..27 clamped to zero pad, stores guarded)
    conv_mfma<16, 32, 54, 260, 29, 136, 25, 125, 8, 1, 4, false>
        <<<dim3(128 * 7 * 8 / 4), 256, 0, stream>>>(p1, wt2, ss2, p2);
    // conv3: RPW=4, R=3 (12 rows exactly)
    conv_mfma<32, 64, 29, 136, 16, 68, 12, 62, 4, 2, 4, false>
        <<<dim3(128 * 3 * 4 * 2 / 4), 256, 0, stream>>>(p2, wt3, ss3, p3);
    // conv4: RPW=2, R=3, NCHW f32 out
    conv_mfma<64, 32, 16, 68, 0, 0, 6, 31, 2, 1, 2, true>
        <<<dim3(128 * 3 * 2 / 4), 256, 0, stream>>>(p3, wt4, ss4, l4);

    fc1_kernel<<<dim3(128, 32), 64, 0, stream>>>(l4, fw1, fb1, h1);
    fc2_mean_kernel<<<1, 64, 0, stream>>>(h1, fw2, fb2, (float*)d_out);
}

// Round 10
// 448.945 us; speedup vs baseline: 1.0486x; 1.0486x over previous
//
#include <hip/hip_runtime.h>
#include <hip/hip_bf16.h>

#define EPSB 1e-5f

typedef short s16x8 __attribute__((ext_vector_type(8)));
typedef float f32x16 __attribute__((ext_vector_type(16)));

// ---------------- workspace layout (bytes) ----------------
//  p1: 128 x [54][260][16]  = 57,507,840 B   (conv1 out / conv2 in)
//  p2: 128 x [29][136][32]  = 32,309,248 B   (conv2 out / conv3 in)
//  p3: 128 x [16][68][64]   = 17,825,792 B   (conv3 out / conv4 in)
#define P1_OFF   0
#define P2_OFF   57507840
#define P3_OFF   89817088
#define L4_OFF   107642880   // 128x32x6x31 f32 NCHW = 3,047,424 B
#define H1_OFF   110690304   // 128x32 f32
#define WT2_OFF  110706688   // [25][32][16] bf16
#define WT3_OFF  110732288   // [25][64][32] bf16
#define WT4_OFF  110834688   // [25][32][64] bf16
#define SS2_OFF  110937088   // 2*32 f32 (scale, shift)
#define SS3_OFF  110937344   // 2*64 f32
#define SS4_OFF  110937856   // 2*32 f32

__device__ __forceinline__ unsigned short bf16bits(float f) {
    __hip_bfloat16 h = __float2bfloat16(f);
    union { __hip_bfloat16 h; unsigned short u; } cv; cv.h = h; return cv.u;
}

// ---- prep bodies (one kernel) ----

template<int HP, int WP, int C, int IH, int IW>
__device__ __forceinline__ void pad_body(__hip_bfloat16* __restrict__ buf, int idx)
{
    if (idx >= 128 * HP * WP) return;
    const int rc = idx % (HP * WP);
    const int row = rc / WP, col = rc % WP;
    const bool pad = (row < 2) | (row >= 2 + IH) | (col < 2) | (col >= 2 + IW);
    if (!pad) return;
    int4* p = reinterpret_cast<int4*>(buf + (size_t)idx * C);
    #pragma unroll
    for (int i = 0; i < C * 2 / 16; ++i) p[i] = int4{0, 0, 0, 0};
}

__device__ __forceinline__ void wtrans_body(const float* __restrict__ src,
                                            __hip_bfloat16* __restrict__ dst,
                                            int CO, int CI, int idx)
{
    if (idx >= CO * CI * 25) return;
    const int co  = idx / (CI * 25);
    const int rem = idx % (CI * 25);
    const int ci  = rem / 25;
    const int tap = rem % 25;
    dst[((size_t)tap * CO + co) * CI + ci] = __float2bfloat16(src[idx]);
}

__device__ __forceinline__ void scsh_body(const float* __restrict__ b,
                                          const float* __restrict__ g,
                                          const float* __restrict__ be,
                                          const float* __restrict__ m,
                                          const float* __restrict__ v,
                                          float* __restrict__ out, int CO, int i)
{
    if (i < CO) {
        const float sc = g[i] * rsqrtf(v[i] + EPSB);
        out[i]      = sc;
        out[CO + i] = fmaf(b[i] - m[i], sc, be[i]);
    }
}

__global__ __launch_bounds__(256)
void prep_kernel(__hip_bfloat16* p1, __hip_bfloat16* p2, __hip_bfloat16* p3,
                 const float* w2, __hip_bfloat16* wt2,
                 const float* w3, __hip_bfloat16* wt3,
                 const float* w4, __hip_bfloat16* wt4,
                 const float* b2, const float* g2, const float* be2,
                 const float* m2, const float* v2, float* ss2,
                 const float* b3, const float* g3, const float* be3,
                 const float* m3, const float* v3, float* ss3,
                 const float* b4, const float* g4, const float* be4,
                 const float* m4, const float* v4, float* ss4)
{
    const int bid = blockIdx.x;
    const int tid = threadIdx.x;
    if      (bid < 7020) pad_body<54, 260, 16, 50, 250>(p1, bid * 256 + tid);
    else if (bid < 8992) pad_body<29, 136, 32, 25, 125>(p2, (bid - 7020) * 256 + tid);
    else if (bid < 9536) pad_body<16,  68, 64, 12,  62>(p3, (bid - 8992) * 256 + tid);
    else if (bid < 9586) wtrans_body(w2, wt2, 32, 16, (bid - 9536) * 256 + tid);
    else if (bid < 9786) wtrans_body(w3, wt3, 64, 32, (bid - 9586) * 256 + tid);
    else if (bid < 9986) wtrans_body(w4, wt4, 32, 64, (bid - 9786) * 256 + tid);
    else {
        const int which = bid - 9986;
        if      (which == 0) scsh_body(b2, g2, be2, m2, v2, ss2, 32, tid);
        else if (which == 1) scsh_body(b3, g3, be3, m3, v3, ss3, 64, tid);
        else                 scsh_body(b4, g4, be4, m4, v4, ss4, 32, tid);
    }
}

// conv1 (round-8 structure): block = one pooled row, LDS row-strip staging.
__global__ __launch_bounds__(256)
void conv1_kernel(const float* __restrict__ x,
                  const float* __restrict__ wgt,
                  const float* __restrict__ bias,
                  const float* __restrict__ g,
                  const float* __restrict__ be,
                  const float* __restrict__ m,
                  const float* __restrict__ v,
                  __hip_bfloat16* __restrict__ p1,
                  int n0)
{
    __shared__ float smem[6 * 504];
    const int n   = blockIdx.y + n0;
    const int ph  = blockIdx.x;
    const int tid = threadIdx.x;

    const int b = n >> 3, l = n & 7;
    const float* ib = x + (size_t)b * 400000 + l * 500;
    const int h0 = 2 * ph - 2;

    for (int i = tid; i < 6 * 504; i += 256) {
        const int rr = i / 504, cc = i % 504;
        const int hh = h0 + rr, ww = cc - 2;
        const bool ok = (hh >= 0) & (hh < 100) & (ww >= 0) & (ww < 500);
        smem[i] = ok ? ib[hh * 4000 + ww] : 0.0f;
    }
    __syncthreads();

    if (tid >= 250) return;
    const int pw = tid;

    float win[6][6];
    #pragma unroll
    for (int r = 0; r < 6; ++r)
        #pragma unroll
        for (int c = 0; c < 6; ++c)
            win[r][c] = smem[r * 504 + 2 * pw + c];

    int packed[8];
    #pragma unroll
    for (int cp = 0; cp < 8; ++cp) {
        unsigned short hb[2];
        #pragma unroll
        for (int sub = 0; sub < 2; ++sub) {
            const int co = 2 * cp + sub;
            float a0 = 0.f, a1 = 0.f, a2 = 0.f, a3 = 0.f;
            #pragma unroll
            for (int kh = 0; kh < 5; ++kh) {
                #pragma unroll
                for (int kw = 0; kw < 5; ++kw) {
                    const float w = wgt[co * 25 + kh * 5 + kw];
                    a0 = fmaf(w, win[kh  ][kw  ], a0);
                    a1 = fmaf(w, win[kh  ][kw+1], a1);
                    a2 = fmaf(w, win[kh+1][kw  ], a2);
                    a3 = fmaf(w, win[kh+1][kw+1], a3);
                }
            }
            const float sc = g[co] * rsqrtf(v[co] + EPSB);
            const float sh = fmaf(bias[co] - m[co], sc, be[co]);
            #define RA(a) fmaxf(fmaf((a), sc, sh), 0.0f)
            hb[sub] = bf16bits(fmaxf(fmaxf(RA(a0), RA(a1)), fmaxf(RA(a2), RA(a3))));
            #undef RA
        }
        packed[cp] = hb[0] | (hb[1] << 16);
    }

    int4* dst = reinterpret_cast<int4*>(
        p1 + (size_t)n * (54 * 260 * 16) + ((2 + ph) * 260 + (2 + pw)) * 16);
    dst[0] = int4{packed[0], packed[1], packed[2], packed[3]};
    dst[1] = int4{packed[4], packed[5], packed[6], packed[7]};
}

// MFMA conv with LDS-staged input tile (RPW=2).
// Block = (n, pool-row pair r, wt-group). Stages NROW=8 input rows x
// WST w-positions x CI channels once; all kw shifts then read LDS.
// 16B granules stored at G^((G>>3)&7): spreads the 32B-lane-stride
// ds_read_b128 pattern across all 8 granule-bank classes (else 8-16 way
// bank conflict). Same XOR on write and read -> layout-transparent.
template<int CI, int CO, int HINP, int WINP, int HOUTP, int WOUTP,
         int PH, int PW, int NT, int WTB, int COTB, bool NCHW_OUT>
__global__ __launch_bounds__(256)
void conv_mfma_lds(const __hip_bfloat16* __restrict__ pin,
                   const __hip_bfloat16* __restrict__ wq,
                   const float* __restrict__ scsh,
                   void* __restrict__ pout)
{
    constexpr int RPW  = 2;
    constexpr int R    = (PH + RPW - 1) / RPW;
    constexpr int NROW = 2 * RPW + 4;          // 8
    constexpr int GPW  = CI / 8;               // 16B granules per w
    constexpr int WST  = WTB * 32 + 8;         // staged w (4 halo + pad)
    constexpr int GPR  = WST * GPW;            // granules/row (mult of 8)
    constexpr int WTG  = NT / WTB;
    __shared__ short smem[NROW * GPR * 8];

    const int nbk = gridDim.x;
    const int swz = (blockIdx.x & 7) * (nbk >> 3) + (blockIdx.x >> 3);
    int t = swz;
    const int wtg = t % WTG; t /= WTG;
    const int r   = t % R;   t /= R;
    const int n   = t;

    const int tid = threadIdx.x;
    const int r0 = 2 * RPW * r;
    const int w0blk = wtg * (WTB * 32);

    for (int i = tid; i < NROW * GPR; i += 256) {
        const int row_j = i / GPR;
        const int gr    = i % GPR;
        const int w = gr / GPW, gsub = gr % GPW;
        int grow = r0 + row_j; if (grow > HINP - 1) grow = HINP - 1;
        const size_t gaddr = (((size_t)n * HINP + grow) * WINP + (w0blk + w)) * CI + gsub * 8;
        const s16x8 val = *reinterpret_cast<const s16x8*>(pin + gaddr);
        const int Gp = i ^ ((i >> 3) & 7);
        *reinterpret_cast<s16x8*>(&smem[Gp * 8]) = val;
    }
    __syncthreads();

    const int wv = tid >> 6, lane = tid & 63;
    const int lw = lane & 31, loct = lane >> 5;
    const int wt_l = wv % WTB;
    const int cot  = wv / WTB;                 // < COTB
    const int wt   = wtg * WTB + wt_l;
    const int co0  = cot * 32;
    const int w0l  = wt_l * 32;

    const __hip_bfloat16* abase = wq + (co0 + lw) * CI + loct * 8;

    f32x16 acc[4];
    #pragma unroll
    for (int q = 0; q < 4; ++q) acc[q] = (f32x16){};

    #pragma unroll
    for (int kw = 0; kw < 5; ++kw) {
        #pragma unroll
        for (int s = 0; s < CI / 16; ++s) {
            s16x8 bfr[NROW];
            #pragma unroll
            for (int j = 0; j < NROW; ++j) {
                int G = j * GPR + (w0l + lw + kw) * GPW + loct + 2 * s;
                G ^= (G >> 3) & 7;
                bfr[j] = *reinterpret_cast<const s16x8*>(&smem[G * 8]);
            }
            #pragma unroll
            for (int kh = 0; kh < 5; ++kh) {
                const s16x8 a = *reinterpret_cast<const s16x8*>(
                    abase + (size_t)((kh * 5 + kw) * CO) * CI + s * 16);
                #pragma unroll
                for (int q = 0; q < 4; ++q)
                    acc[q] = __builtin_amdgcn_mfma_f32_32x32x16_bf16(a, bfr[kh + q], acc[q], 0, 0, 0);
            }
        }
    }

    const int pw = wt * 16 + (lw >> 1);
    const bool act = ((lane & 1) == 0) && (pw < PW);
    #pragma unroll
    for (int p = 0; p < RPW; ++p) {
        const int pr = RPW * r + p;
        const bool rok = (pr < PH);
        #pragma unroll
        for (int reg = 0; reg < 16; ++reg) {
            const int co = co0 + (reg & 3) + 8 * (reg >> 2) + 4 * loct;
            const float sc = scsh[co], sh = scsh[CO + co];
            const float v0 = fmaxf(fmaf(acc[2 * p    ][reg], sc, sh), 0.0f);
            const float v1 = fmaxf(fmaf(acc[2 * p + 1][reg], sc, sh), 0.0f);
            float vm = fmaxf(v0, v1);
            vm = fmaxf(vm, __shfl_xor(vm, 1, 64));
            if (act && rok) {
                if (NCHW_OUT) {
                    ((float*)pout)[(((size_t)n * CO + co) * PH + pr) * PW + pw] = vm;
                } else {
                    ((__hip_bfloat16*)pout)[(size_t)n * (HOUTP * WOUTP * CO)
                        + ((2 + pr) * WOUTP + (2 + pw)) * CO + co] = __float2bfloat16(vm);
                }
            }
        }
    }
}

// Global-load MFMA conv (round-8 version) — still used for conv4.
template<int CI, int CO, int HINP, int WINP, int HOUTP, int WOUTP,
         int PH, int PW, int NT, int NCOT, int RPW, bool NCHW_OUT>
__global__ __launch_bounds__(256)
void conv_mfma(const __hip_bfloat16* __restrict__ pin,
               const __hip_bfloat16* __restrict__ wq,
               const float* __restrict__ scsh,
               void* __restrict__ pout)
{
    constexpr int R = (PH + RPW - 1) / RPW;
    constexpr int NROW = 2 * RPW + 4;
    const int lane = threadIdx.x & 63;
    const int nbk  = gridDim.x;
    const int swz  = (blockIdx.x & 7) * (nbk >> 3) + (blockIdx.x >> 3);
    int t = swz * 4 + (threadIdx.x >> 6);
    const int cot = t % NCOT; t /= NCOT;
    const int wt  = t % NT;   t /= NT;
    const int r   = t % R;    t /= R;
    const int n   = t;
    if (n >= 128) return;

    const int lw = lane & 31, loct = lane >> 5;
    const int co0 = cot * 32;
    const int w0  = wt * 32;

    const __hip_bfloat16* bbase = pin + (size_t)n * (HINP * WINP * CI)
                                + (w0 + lw) * CI + loct * 8;
    const __hip_bfloat16* abase = wq + (co0 + lw) * CI + loct * 8;

    f32x16 acc[2 * RPW];
    #pragma unroll
    for (int q = 0; q < 2 * RPW; ++q) acc[q] = (f32x16){};

    #pragma unroll
    for (int kw = 0; kw < 5; ++kw) {
        #pragma unroll
        for (int s = 0; s < CI / 16; ++s) {
            s16x8 bfr[NROW];
            #pragma unroll
            for (int j = 0; j < NROW; ++j) {
                const int row = (2 * RPW * r + j < HINP) ? (2 * RPW * r + j) : (HINP - 1);
                bfr[j] = *reinterpret_cast<const s16x8*>(bbase + (row * WINP + kw) * CI + s * 16);
            }
            #pragma unroll
            for (int kh = 0; kh < 5; ++kh) {
                const s16x8 a = *reinterpret_cast<const s16x8*>(
                    abase + (size_t)((kh * 5 + kw) * CO) * CI + s * 16);
                #pragma unroll
                for (int q = 0; q < 2 * RPW; ++q)
                    acc[q] = __builtin_amdgcn_mfma_f32_32x32x16_bf16(a, bfr[kh + q], acc[q], 0, 0, 0);
            }
        }
    }

    const int pw = wt * 16 + (lw >> 1);
    const bool act = ((lane & 1) == 0) && (pw < PW);
    #pragma unroll
    for (int p = 0; p < RPW; ++p) {
        const int pr = RPW * r + p;
        const bool rok = (pr < PH);
        #pragma unroll
        for (int reg = 0; reg < 16; ++reg) {
            const int co = co0 + (reg & 3) + 8 * (reg >> 2) + 4 * loct;
            const float sc = scsh[co], sh = scsh[CO + co];
            const float v0 = fmaxf(fmaf(acc[2 * p    ][reg], sc, sh), 0.0f);
            const float v1 = fmaxf(fmaf(acc[2 * p + 1][reg], sc, sh), 0.0f);
            float vm = fmaxf(v0, v1);
            vm = fmaxf(vm, __shfl_xor(vm, 1, 64));
            if (act && rok) {
                if (NCHW_OUT) {
                    ((float*)pout)[(((size_t)n * CO + co) * PH + pr) * PW + pw] = vm;
                } else {
                    ((__hip_bfloat16*)pout)[(size_t)n * (HOUTP * WOUTP * CO)
                        + ((2 + pr) * WOUTP + (2 + pw)) * CO + co] = __float2bfloat16(vm);
                }
            }
        }
    }
}

// h (128, 5952 NCHW f32) @ fw1^T + fb1 -> h1 (128,32)
__global__ __launch_bounds__(64)
void fc1_kernel(const float* __restrict__ h,
                const float* __restrict__ fw1,
                const float* __restrict__ fb1,
                float* __restrict__ h1)
{
    const int n = blockIdx.x;
    const int j = blockIdx.y;
    const int lane = threadIdx.x;
    const float* hp = h   + (size_t)n * 5952;
    const float* wp = fw1 + (size_t)j * 5952;
    float s = 0.0f;
    for (int k = lane; k < 5952; k += 64) s = fmaf(hp[k], wp[k], s);
    #pragma unroll
    for (int off = 32; off > 0; off >>= 1) s += __shfl_down(s, off, 64);
    if (lane == 0) h1[n * 32 + j] = s + fb1[j];
}

__global__ __launch_bounds__(64)
void fc2_mean_kernel(const float* __restrict__ h1,
                     const float* __restrict__ fw2,
                     const float* __restrict__ fb2,
                     float* __restrict__ out)
{
    const int t = threadIdx.x;
    if (t >= 32) return;
    const int b = t >> 1, c = t & 1;
    float s = 0.0f;
    for (int l = 0; l < 8; ++l) {
        const float* hp = h1 + (size_t)(b * 8 + l) * 32;
        #pragma unroll
        for (int j = 0; j < 32; ++j) s = fmaf(hp[j], fw2[c * 32 + j], s);
    }
    out[t] = fmaf(s, 0.125f, fb2[c]);
}

extern "C" void kernel_launch(void* const* d_in, const int* in_sizes, int n_in,
                              void* d_out, int out_size, void* d_ws, size_t ws_size,
                              hipStream_t stream)
{
    const float* x   = (const float*)d_in[0];
    const float* w1  = (const float*)d_in[1];
    const float* b1  = (const float*)d_in[2];
    const float* g1  = (const float*)d_in[3];
    const float* be1 = (const float*)d_in[4];
    const float* m1  = (const float*)d_in[5];
    const float* v1  = (const float*)d_in[6];
    const float* w2  = (const float*)d_in[7];
    const float* b2  = (const float*)d_in[8];
    const float* g2  = (const float*)d_in[9];
    const float* be2 = (const float*)d_in[10];
    const float* m2  = (const float*)d_in[11];
    const float* v2  = (const float*)d_in[12];
    const float* w3  = (const float*)d_in[13];
    const float* b3  = (const float*)d_in[14];
    const float* g3  = (const float*)d_in[15];
    const float* be3 = (const float*)d_in[16];
    const float* m3  = (const float*)d_in[17];
    const float* v3  = (const float*)d_in[18];
    const float* w4  = (const float*)d_in[19];
    const float* b4  = (const float*)d_in[20];
    const float* g4  = (const float*)d_in[21];
    const float* be4 = (const float*)d_in[22];
    const float* m4  = (const float*)d_in[23];
    const float* v4  = (const float*)d_in[24];
    const float* fw1 = (const float*)d_in[25];
    const float* fb1 = (const float*)d_in[26];
    const float* fw2 = (const float*)d_in[27];
    const float* fb2 = (const float*)d_in[28];

    char* ws = (char*)d_ws;
    __hip_bfloat16* p1  = (__hip_bfloat16*)(ws + P1_OFF);
    __hip_bfloat16* p2  = (__hip_bfloat16*)(ws + P2_OFF);
    __hip_bfloat16* p3  = (__hip_bfloat16*)(ws + P3_OFF);
    float*          l4  = (float*)(ws + L4_OFF);
    float*          h1  = (float*)(ws + H1_OFF);
    __hip_bfloat16* wt2 = (__hip_bfloat16*)(ws + WT2_OFF);
    __hip_bfloat16* wt3 = (__hip_bfloat16*)(ws + WT3_OFF);
    __hip_bfloat16* wt4 = (__hip_bfloat16*)(ws + WT4_OFF);
    float*          ss2 = (float*)(ws + SS2_OFF);
    float*          ss3 = (float*)(ws + SS3_OFF);
    float*          ss4 = (float*)(ws + SS4_OFF);

    prep_kernel<<<dim3(9989), 256, 0, stream>>>(
        p1, p2, p3, w2, wt2, w3, wt3, w4, wt4,
        b2, g2, be2, m2, v2, ss2,
        b3, g3, be3, m3, v3, ss3,
        b4, g4, be4, m4, v4, ss4);

    for (int c = 0; c < 4; ++c)
        conv1_kernel<<<dim3(50, 32), 256, 0, stream>>>(
            x, w1, b1, g1, be1, m1, v1, p1, c * 32);

    // conv2: LDS-staged, block = (n, r<13, wtg<2), 4 wt-tiles/block
    conv_mfma_lds<16, 32, 54, 260, 29, 136, 25, 125, 8, 4, 1, false>
        <<<dim3(128 * 13 * 2), 256, 0, stream>>>(p1, wt2, ss2, p2);
    // conv3: LDS-staged, block = (n, r<6, wtp<2), 2 wt x 2 cot per block
    conv_mfma_lds<32, 64, 29, 136, 16, 68, 12, 62, 4, 2, 2, false>
        <<<dim3(128 * 6 * 2), 256, 0, stream>>>(p2, wt3, ss3, p3);
    // conv4: global-load version, RPW=2
    conv_mfma<64, 32, 16, 68, 0, 0, 6, 31, 2, 1, 2, true>
        <<<dim3(128 * 3 * 2 / 4), 256, 0, stream>>>(p3, wt4, ss4, l4);

    fc1_kernel<<<dim3(128, 32), 64, 0, stream>>>(l4, fw1, fb1, h1);
    fc2_mean_kernel<<<1, 64, 0, stream>>>(h1, fw2, fb2, (float*)d_out);
}